// Round 10
// baseline (453.840 us; speedup 1.0000x reference)
//
#include <hip/hip_runtime.h>
#include <hip/hip_bf16.h>

#define N 8192
#define IN_DIM 512
#define OUT_DIM 64
#define ALPHA 0.2f
#define LOG2E 1.44269504f

typedef __hip_bfloat16 bf16;
typedef __attribute__((ext_vector_type(8))) short bf16x8;   // 8 bf16 = 4 VGPRs (MFMA A/B frag)
typedef __attribute__((ext_vector_type(4))) float f32x4;    // MFMA C/D frag
typedef __attribute__((ext_vector_type(4))) int   int4v;
typedef __attribute__((ext_vector_type(4))) float float4v;

__device__ __forceinline__ float u2f(unsigned short u) {
    union { unsigned int i; float f; } c; c.i = ((unsigned int)u) << 16; return c.f;
}

// Exact truncation hi/lo split of two fp32 into packed bf16 words.
__device__ __forceinline__ uint2 splitpack2(float f0, float f1) {
    unsigned u0 = __float_as_uint(f0), u1 = __float_as_uint(f1);
    unsigned h0 = u0 & 0xFFFF0000u, h1 = u1 & 0xFFFF0000u;
    float l0 = f0 - __uint_as_float(h0);
    float l1 = f1 - __uint_as_float(h1);
    uint2 r;
    r.x = (h0 >> 16) | h1;
    r.y = (__float_as_uint(l0) >> 16) | (__float_as_uint(l1) & 0xFFFF0000u);
    return r;
}

__device__ __forceinline__ bf16x8 as_bf16x8(int a, int b, int c, int d) {
    union { int4v i; bf16x8 b; } u;
    u.i = (int4v){a, b, c, d};
    return u.b;
}

// ordered-float <-> unsigned monotone encoding (for atomicMax on float)
__device__ __forceinline__ unsigned fenc(float f) {
    unsigned u = __float_as_uint(f);
    return (u & 0x80000000u) ? ~u : (u | 0x80000000u);
}
__device__ __forceinline__ float fdec(unsigned e) {
    return (e & 0x80000000u) ? __uint_as_float(e & 0x7FFFFFFFu) : __uint_as_float(~e);
}

// ---------- prep: sniff dtype (per-block) + W -> WT hi/lo [64][512]; init h2max ----------
__global__ __launch_bounds__(256) void k_prep(const unsigned short* __restrict__ feat_u16,
                                              const void* __restrict__ Wv,
                                              int* __restrict__ flag,
                                              unsigned short* __restrict__ WT_hi,
                                              unsigned short* __restrict__ WT_lo,
                                              unsigned* __restrict__ h2enc) {
    __shared__ int sflag;
    int tid = threadIdx.x;
    if (tid < 64) {
        float v = u2f(feat_u16[2 * tid]);
        float av = fabsf(v);
        int ok = (v == 0.f) || (av > 1e-8f && av < 1e8f);
        unsigned long long m = __ballot(ok);
        if (tid == 0) sflag = (__popcll(m) >= 48) ? 1 : 0;
    }
    __syncthreads();
    int isbf = sflag;
    if (blockIdx.x == 0 && tid == 0) { *flag = isbf; *h2enc = fenc(-3e38f); }
    int idx = blockIdx.x * 256 + tid;              // 0..32767
    int k = idx >> 6, c = idx & 63;
    float w = isbf ? u2f(((const unsigned short*)Wv)[idx]) : ((const float*)Wv)[idx];
    unsigned u = __float_as_uint(w);
    unsigned hi = u & 0xFFFF0000u;
    float lo = w - __uint_as_float(hi);
    WT_hi[c * IN_DIM + k] = (unsigned short)(hi >> 16);
    WT_lo[c * IN_DIM + k] = (unsigned short)(__float_as_uint(lo) >> 16);
}

// ---------- Kernel A (MFMA): h = feat @ W; hT hi/lo; h1,h2 (x log2e) ----------
// Block = 256 thr (4 waves), 16 rows; waves split K=512 four ways, merge via LDS.
__global__ __launch_bounds__(256) void k_h(const void* __restrict__ featv,
                                           const unsigned short* __restrict__ WT_hi,
                                           const unsigned short* __restrict__ WT_lo,
                                           const void* __restrict__ av,
                                           const int* __restrict__ flag,
                                           float* __restrict__ h1,
                                           float* __restrict__ h2,
                                           unsigned short* __restrict__ hT_hi,
                                           unsigned short* __restrict__ hT_lo,
                                           unsigned* __restrict__ h2enc) {
    __shared__ float C[16][66];        // merged h tile, +2 pad
    const int tid = threadIdx.x;
    const int wave = tid >> 6;
    const int lane = tid & 63;
    const int rsub = lane & 15;
    const int g = lane >> 4;
    const int wrow0 = blockIdx.x * 16;
    const int isbf = *flag;

    f32x4 acc0 = {0.f,0.f,0.f,0.f}, acc1 = {0.f,0.f,0.f,0.f};
    f32x4 acc2 = {0.f,0.f,0.f,0.f}, acc3 = {0.f,0.f,0.f,0.f};

    const int kbeg = wave * (IN_DIM / 4);
    for (int k0 = kbeg; k0 < kbeg + IN_DIM / 4; k0 += 32) {
        const int ka = k0 + g * 8;
        bf16x8 Ah, Al;
        if (isbf) {
            Ah = *(const bf16x8*)((const unsigned short*)featv + (size_t)(wrow0 + rsub) * IN_DIM + ka);
            Al = as_bf16x8(0, 0, 0, 0);
        } else {
            const float* fp = (const float*)featv + (size_t)(wrow0 + rsub) * IN_DIM + ka;
            float4v f0 = *(const float4v*)fp;
            float4v f1 = *(const float4v*)(fp + 4);
            uint2 q0 = splitpack2(f0[0], f0[1]);
            uint2 q1 = splitpack2(f0[2], f0[3]);
            uint2 q2 = splitpack2(f1[0], f1[1]);
            uint2 q3 = splitpack2(f1[2], f1[3]);
            Ah = as_bf16x8((int)q0.x, (int)q1.x, (int)q2.x, (int)q3.x);
            Al = as_bf16x8((int)q0.y, (int)q1.y, (int)q2.y, (int)q3.y);
        }
        const unsigned short* wh = WT_hi + (size_t)rsub * IN_DIM + ka;
        const unsigned short* wl = WT_lo + (size_t)rsub * IN_DIM + ka;
        bf16x8 B0h = *(const bf16x8*)(wh);
        bf16x8 B1h = *(const bf16x8*)(wh + 16 * IN_DIM);
        bf16x8 B2h = *(const bf16x8*)(wh + 32 * IN_DIM);
        bf16x8 B3h = *(const bf16x8*)(wh + 48 * IN_DIM);
        bf16x8 B0l = *(const bf16x8*)(wl);
        bf16x8 B1l = *(const bf16x8*)(wl + 16 * IN_DIM);
        bf16x8 B2l = *(const bf16x8*)(wl + 32 * IN_DIM);
        bf16x8 B3l = *(const bf16x8*)(wl + 48 * IN_DIM);

        acc0 = __builtin_amdgcn_mfma_f32_16x16x32_bf16(Ah, B0h, acc0, 0, 0, 0);
        acc1 = __builtin_amdgcn_mfma_f32_16x16x32_bf16(Ah, B1h, acc1, 0, 0, 0);
        acc2 = __builtin_amdgcn_mfma_f32_16x16x32_bf16(Ah, B2h, acc2, 0, 0, 0);
        acc3 = __builtin_amdgcn_mfma_f32_16x16x32_bf16(Ah, B3h, acc3, 0, 0, 0);
        acc0 = __builtin_amdgcn_mfma_f32_16x16x32_bf16(Ah, B0l, acc0, 0, 0, 0);
        acc1 = __builtin_amdgcn_mfma_f32_16x16x32_bf16(Ah, B1l, acc1, 0, 0, 0);
        acc2 = __builtin_amdgcn_mfma_f32_16x16x32_bf16(Ah, B2l, acc2, 0, 0, 0);
        acc3 = __builtin_amdgcn_mfma_f32_16x16x32_bf16(Ah, B3l, acc3, 0, 0, 0);
        acc0 = __builtin_amdgcn_mfma_f32_16x16x32_bf16(Al, B0h, acc0, 0, 0, 0);
        acc1 = __builtin_amdgcn_mfma_f32_16x16x32_bf16(Al, B1h, acc1, 0, 0, 0);
        acc2 = __builtin_amdgcn_mfma_f32_16x16x32_bf16(Al, B2h, acc2, 0, 0, 0);
        acc3 = __builtin_amdgcn_mfma_f32_16x16x32_bf16(Al, B3h, acc3, 0, 0, 0);
    }

    // merge the 4 K-partials through LDS (C/D layout: col=lane&15, row=4*g+reg)
    if (wave == 0) {
#pragma unroll
        for (int r = 0; r < 4; ++r) {
            C[g * 4 + r][rsub]      = acc0[r];
            C[g * 4 + r][16 + rsub] = acc1[r];
            C[g * 4 + r][32 + rsub] = acc2[r];
            C[g * 4 + r][48 + rsub] = acc3[r];
        }
    }
    __syncthreads();
#pragma unroll
    for (int w2 = 1; w2 < 4; ++w2) {
        if (wave == w2) {
#pragma unroll
            for (int r = 0; r < 4; ++r) {
                C[g * 4 + r][rsub]      += acc0[r];
                C[g * 4 + r][16 + rsub] += acc1[r];
                C[g * 4 + r][32 + rsub] += acc2[r];
                C[g * 4 + r][48 + rsub] += acc3[r];
            }
        }
        __syncthreads();
    }

    // ---- epilogue 1: hT hi/lo split-stores (natural row order) ----
    {
        int c = tid >> 2;
        int r0 = (tid & 3) * 4;
        float v0 = C[r0 + 0][c], v1 = C[r0 + 1][c], v2 = C[r0 + 2][c], v3 = C[r0 + 3][c];
        uint2 s01 = splitpack2(v0, v1);
        uint2 s23 = splitpack2(v2, v3);
        size_t off = (size_t)c * N + wrow0 + r0;
        { uint2 ph; ph.x = s01.x; ph.y = s23.x; *(uint2*)(hT_hi + off) = ph; }
        { uint2 pl; pl.x = s01.y; pl.y = s23.y; *(uint2*)(hT_lo + off) = pl; }
    }

    // ---- epilogue 2: h1/h2 (scaled by LOG2E) + h2 global max ----
    if (wave == 0 && lane < 16) {
        const float* af = (const float*)av;
        const unsigned short* au = (const unsigned short*)av;
        float s1 = 0.f, s2 = 0.f;
#pragma unroll 8
        for (int c = 0; c < 64; ++c) {
            float a1 = isbf ? u2f(au[c])      : af[c];
            float a2 = isbf ? u2f(au[64 + c]) : af[64 + c];
            float hv = C[lane][c];
            s1 += hv * a1;
            s2 += hv * a2;
        }
        s1 *= LOG2E; s2 *= LOG2E;
        h1[wrow0 + lane] = s1;
        h2[wrow0 + lane] = s2;
        float wm = s2;
#pragma unroll
        for (int off = 8; off; off >>= 1) wm = fmaxf(wm, __shfl_xor(wm, off));
        if (lane == 0) atomicMax(h2enc, fenc(wm));
    }
}

// ---------- Kernel B: fused ballot-stage + masked-exp MFMA GEMM ----------
// nkb=16 => (row-block, K-slice) grid PARTITIONS adj: each block reads its own
// 64 x klen adj tile ONCE, fully coalesced (2KB contiguous per row), ballots it
// into a 4.6KB LDS bitmask, then runs the bitmask hot loop (zero global adj
// traffic, B-frags L2-resident). No separate pack pass, no abits buffer.
__global__ __launch_bounds__(256, 2) void k_attn(const int* __restrict__ adj,
                                                 const float* __restrict__ h1,
                                                 const float* __restrict__ h2,
                                                 const unsigned short* __restrict__ hT_hi,
                                                 const unsigned short* __restrict__ hT_lo,
                                                 const unsigned* __restrict__ h2enc,
                                                 float* __restrict__ pacc,
                                                 float* __restrict__ plner,
                                                 int klen) {
    __shared__ float accs[64][66];       // +2 pad
    __shared__ float lredL[4][64];
    __shared__ unsigned msk[64][34];     // klen<=1024 (wpr<=32); stride 34: 8B-aligned rows,
                                         // banks 2r%32 distinct for r=0..15
    const int wave = threadIdx.x >> 6;
    const int lane = threadIdx.x & 63;
    const int rsub = lane & 15;
    const int g = lane >> 4;
    const int row0 = blockIdx.x * 64;
    const int kbid = blockIdx.y;
    const int colbase = kbid * klen;

    // ---- stage: ballot-pack this block's adj tile into msk (wave w: rows 16w..16w+15) ----
    for (int r = wave * 16; r < wave * 16 + 16; ++r) {
        const int* p = adj + (size_t)(row0 + r) * N + colbase;
        for (int cb = 0; cb < klen; cb += 512) {
            // 8 independent 256B loads first (2KB in flight), then the ballots
            int v0 = p[cb + 0 * 64 + lane];
            int v1 = p[cb + 1 * 64 + lane];
            int v2 = p[cb + 2 * 64 + lane];
            int v3 = p[cb + 3 * 64 + lane];
            int v4 = p[cb + 4 * 64 + lane];
            int v5 = p[cb + 5 * 64 + lane];
            int v6 = p[cb + 6 * 64 + lane];
            int v7 = p[cb + 7 * 64 + lane];
            unsigned long long m0 = __ballot(v0 > 0);
            unsigned long long m1 = __ballot(v1 > 0);
            unsigned long long m2 = __ballot(v2 > 0);
            unsigned long long m3 = __ballot(v3 > 0);
            unsigned long long m4 = __ballot(v4 > 0);
            unsigned long long m5 = __ballot(v5 > 0);
            unsigned long long m6 = __ballot(v6 > 0);
            unsigned long long m7 = __ballot(v7 > 0);
            if (lane == 0) {
                int w0 = cb >> 5;
                { uint2 q; q.x = (unsigned)m0; q.y = (unsigned)(m0 >> 32); *(uint2*)&msk[r][w0 + 0]  = q; }
                { uint2 q; q.x = (unsigned)m1; q.y = (unsigned)(m1 >> 32); *(uint2*)&msk[r][w0 + 2]  = q; }
                { uint2 q; q.x = (unsigned)m2; q.y = (unsigned)(m2 >> 32); *(uint2*)&msk[r][w0 + 4]  = q; }
                { uint2 q; q.x = (unsigned)m3; q.y = (unsigned)(m3 >> 32); *(uint2*)&msk[r][w0 + 6]  = q; }
                { uint2 q; q.x = (unsigned)m4; q.y = (unsigned)(m4 >> 32); *(uint2*)&msk[r][w0 + 8]  = q; }
                { uint2 q; q.x = (unsigned)m5; q.y = (unsigned)(m5 >> 32); *(uint2*)&msk[r][w0 + 10] = q; }
                { uint2 q; q.x = (unsigned)m6; q.y = (unsigned)(m6 >> 32); *(uint2*)&msk[r][w0 + 12] = q; }
                { uint2 q; q.x = (unsigned)m7; q.y = (unsigned)(m7 >> 32); *(uint2*)&msk[r][w0 + 14] = q; }
            }
        }
    }

    const float h2m = fdec(*h2enc);
    float h1r[4], c0[4];
#pragma unroll
    for (int mt = 0; mt < 4; ++mt) {
        h1r[mt] = h1[row0 + mt * 16 + rsub];
        float u = h1r[mt] + h2m;
        c0[mt] = -fmaxf(u, ALPHA * u);     // -M' (scaled leaky row-max bound)
    }

    f32x4 acc[4][4];
#pragma unroll
    for (int mt = 0; mt < 4; ++mt)
#pragma unroll
        for (int ct = 0; ct < 4; ++ct) acc[mt][ct] = (f32x4){0.f, 0.f, 0.f, 0.f};
    float lacc[4] = {0.f, 0.f, 0.f, 0.f};

    const unsigned short* bph = hT_hi + (size_t)rsub * N;
    const unsigned short* bpl = hT_lo + (size_t)rsub * N;

    __syncthreads();                      // masks staged

    const int kbeg = colbase + wave * (klen >> 2);
    const int kend = kbeg + (klen >> 2);
    const int sh = g * 8;
    for (int k0 = kbeg; k0 < kend; k0 += 32) {
        const int kb = k0 + g * 8;
        const int wi = (k0 - colbase) >> 5;

        // B-fragments: loaded once, reused by all 4 M-tiles
        const unsigned short* bh = bph + kb;
        const unsigned short* bl = bpl + kb;
        bf16x8 B0h = *(const bf16x8*)(bh);
        bf16x8 B1h = *(const bf16x8*)(bh + 16 * (size_t)N);
        bf16x8 B2h = *(const bf16x8*)(bh + 32 * (size_t)N);
        bf16x8 B3h = *(const bf16x8*)(bh + 48 * (size_t)N);
        bf16x8 B0l = *(const bf16x8*)(bl);
        bf16x8 B1l = *(const bf16x8*)(bl + 16 * (size_t)N);
        bf16x8 B2l = *(const bf16x8*)(bl + 32 * (size_t)N);
        bf16x8 B3l = *(const bf16x8*)(bl + 48 * (size_t)N);

        float4v hA = *(const float4v*)(h2 + kb);
        float4v hB = *(const float4v*)(h2 + kb + 4);

#pragma unroll
        for (int mt = 0; mt < 4; ++mt) {
            const unsigned mask = msk[mt * 16 + rsub][wi];

            float w[8];
#pragma unroll
            for (int j = 0; j < 4; ++j) {
                float u = h1r[mt] + hA[j];
                float s = fmaxf(u, ALPHA * u);
                float e = exp2f(s + c0[mt]);
                w[j] = ((mask >> (sh + j)) & 1u) ? e : 0.f;
            }
#pragma unroll
            for (int j = 0; j < 4; ++j) {
                float u = h1r[mt] + hB[j];
                float s = fmaxf(u, ALPHA * u);
                float e = exp2f(s + c0[mt]);
                w[4 + j] = ((mask >> (sh + 4 + j)) & 1u) ? e : 0.f;
            }
#pragma unroll
            for (int j = 0; j < 8; ++j) lacc[mt] += w[j];

            uint2 p0 = splitpack2(w[0], w[1]);
            uint2 p1 = splitpack2(w[2], w[3]);
            uint2 p2 = splitpack2(w[4], w[5]);
            uint2 p3 = splitpack2(w[6], w[7]);
            bf16x8 Ahi = as_bf16x8((int)p0.x, (int)p1.x, (int)p2.x, (int)p3.x);
            bf16x8 Alo = as_bf16x8((int)p0.y, (int)p1.y, (int)p2.y, (int)p3.y);

            acc[mt][0] = __builtin_amdgcn_mfma_f32_16x16x32_bf16(Ahi, B0h, acc[mt][0], 0, 0, 0);
            acc[mt][1] = __builtin_amdgcn_mfma_f32_16x16x32_bf16(Ahi, B1h, acc[mt][1], 0, 0, 0);
            acc[mt][2] = __builtin_amdgcn_mfma_f32_16x16x32_bf16(Ahi, B2h, acc[mt][2], 0, 0, 0);
            acc[mt][3] = __builtin_amdgcn_mfma_f32_16x16x32_bf16(Ahi, B3h, acc[mt][3], 0, 0, 0);
            acc[mt][0] = __builtin_amdgcn_mfma_f32_16x16x32_bf16(Ahi, B0l, acc[mt][0], 0, 0, 0);
            acc[mt][1] = __builtin_amdgcn_mfma_f32_16x16x32_bf16(Ahi, B1l, acc[mt][1], 0, 0, 0);
            acc[mt][2] = __builtin_amdgcn_mfma_f32_16x16x32_bf16(Ahi, B2l, acc[mt][2], 0, 0, 0);
            acc[mt][3] = __builtin_amdgcn_mfma_f32_16x16x32_bf16(Ahi, B3l, acc[mt][3], 0, 0, 0);
            acc[mt][0] = __builtin_amdgcn_mfma_f32_16x16x32_bf16(Alo, B0h, acc[mt][0], 0, 0, 0);
            acc[mt][1] = __builtin_amdgcn_mfma_f32_16x16x32_bf16(Alo, B1h, acc[mt][1], 0, 0, 0);
            acc[mt][2] = __builtin_amdgcn_mfma_f32_16x16x32_bf16(Alo, B2h, acc[mt][2], 0, 0, 0);
            acc[mt][3] = __builtin_amdgcn_mfma_f32_16x16x32_bf16(Alo, B3h, acc[mt][3], 0, 0, 0);
        }
    }

    // denominator partials
#pragma unroll
    for (int mt = 0; mt < 4; ++mt) {
        float l = lacc[mt];
        l += __shfl_xor(l, 16);
        l += __shfl_xor(l, 32);
        if (g == 0) lredL[wave][mt * 16 + rsub] = l;
    }

    // sequential LDS merge of the 4 K-partials
    if (wave == 0) {
#pragma unroll
        for (int mt = 0; mt < 4; ++mt)
#pragma unroll
            for (int ct = 0; ct < 4; ++ct)
#pragma unroll
                for (int r = 0; r < 4; ++r)
                    accs[mt * 16 + g * 4 + r][ct * 16 + rsub] = acc[mt][ct][r];
    }
    __syncthreads();
#pragma unroll
    for (int w2 = 1; w2 < 4; ++w2) {
        if (wave == w2) {
#pragma unroll
            for (int mt = 0; mt < 4; ++mt)
#pragma unroll
                for (int ct = 0; ct < 4; ++ct)
#pragma unroll
                    for (int r = 0; r < 4; ++r)
                        accs[mt * 16 + g * 4 + r][ct * 16 + rsub] += acc[mt][ct][r];
        }
        __syncthreads();
    }

    // coalesced writeout of the block's 64x64 tile + row denominators
    float* pa = pacc + (size_t)kbid * (N * OUT_DIM);
#pragma unroll
    for (int p = 0; p < 16; ++p) {
        int idx = p * 256 + threadIdx.x;
        int rl = idx >> 6, col = idx & 63;
        pa[(size_t)(row0 + rl) * OUT_DIM + col] = accs[rl][col];
    }
    if (threadIdx.x < 64)
        plner[(size_t)kbid * N + row0 + threadIdx.x] =
            lredL[0][threadIdx.x] + lredL[1][threadIdx.x] + lredL[2][threadIdx.x] + lredL[3][threadIdx.x];
}

// ---------- Kernel C: merge K-partials, normalize, ELU, store ----------
__global__ __launch_bounds__(256) void k_out(const float* __restrict__ pacc,
                                             const float* __restrict__ plner,
                                             const int* __restrict__ flag,
                                             void* __restrict__ outv,
                                             int nkb) {
    int idx = blockIdx.x * 256 + threadIdx.x;
    int row = idx >> 6;
    float v = 0.f, l = 0.f;
    for (int kb = 0; kb < nkb; ++kb) {
        v += pacc[(size_t)kb * (N * OUT_DIM) + idx];
        l += plner[(size_t)kb * N + row];
    }
    float o = l > 0.f ? v / l : 0.f;
    o = o > 0.f ? o : exp2f(o * LOG2E) - 1.f;               // ELU
    if (*flag) ((bf16*)outv)[idx] = __float2bfloat16(o);
    else       ((float*)outv)[idx] = o;
}

extern "C" void kernel_launch(void* const* d_in, const int* in_sizes, int n_in,
                              void* d_out, int out_size, void* d_ws, size_t ws_size,
                              hipStream_t stream) {
    const void* feat = d_in[0];
    const int* adj = (const int*)d_in[1];
    const void* W = d_in[2];
    const void* a = d_in[3];

    char* ws = (char*)d_ws;
    int*      flag  = (int*)(ws);
    unsigned* h2enc = (unsigned*)(ws + 256);
    float* h1       = (float*)(ws + 4096);                              // 32 KB
    float* h2       = (float*)(ws + 36864);                             // 32 KB
    unsigned short* hT_hi = (unsigned short*)(ws + 69632);              // 1 MB
    unsigned short* hT_lo = (unsigned short*)(ws + 69632 + 1048576);    // 1 MB
    unsigned short* WT_hi = (unsigned short*)(ws + 2166784);            // 64 KB
    unsigned short* WT_lo = (unsigned short*)(ws + 2166784 + 65536);    // 64 KB
    char* dynbase = ws + 2297856;

    size_t cap = ws_size ? ws_size : ((size_t)1 << 30);
    int nkb = 16;
    while (nkb > 8) {
        size_t need = (size_t)(dynbase - ws) + (size_t)nkb * ((size_t)N * OUT_DIM * 4 + (size_t)N * 4);
        if (need <= cap) break;
        nkb >>= 1;
    }
    float* pacc  = (float*)dynbase;
    float* plner = (float*)(dynbase + (size_t)nkb * N * OUT_DIM * 4);

    hipLaunchKernelGGL(k_prep, dim3((IN_DIM * OUT_DIM) / 256), dim3(256), 0, stream,
                       (const unsigned short*)feat, W, flag, WT_hi, WT_lo, h2enc);
    hipLaunchKernelGGL(k_h, dim3(N / 16), dim3(256), 0, stream,
                       feat, WT_hi, WT_lo, a, flag, h1, h2, hT_hi, hT_lo, h2enc);
    hipLaunchKernelGGL(k_attn, dim3(N / 64, nkb), dim3(256), 0, stream,
                       adj, h1, h2, hT_hi, hT_lo, h2enc, pacc, plner, N / nkb);
    hipLaunchKernelGGL(k_out, dim3((N * OUT_DIM) / 256), dim3(256), 0, stream,
                       pacc, plner, flag, d_out, nkb);
}

// Round 11
// 417.943 us; speedup vs baseline: 1.0859x; 1.0859x over previous
//
#include <hip/hip_runtime.h>
#include <hip/hip_bf16.h>

#define N 8192
#define IN_DIM 512
#define OUT_DIM 64
#define ALPHA 0.2f
#define LOG2E 1.44269504f

typedef __hip_bfloat16 bf16;
typedef __attribute__((ext_vector_type(8))) short bf16x8;   // 8 bf16 = 4 VGPRs (MFMA A/B frag)
typedef __attribute__((ext_vector_type(4))) float f32x4;    // MFMA C/D frag
typedef __attribute__((ext_vector_type(4))) int   int4v;
typedef __attribute__((ext_vector_type(4))) float float4v;

__device__ __forceinline__ float u2f(unsigned short u) {
    union { unsigned int i; float f; } c; c.i = ((unsigned int)u) << 16; return c.f;
}

// Exact truncation hi/lo split of two fp32 into packed bf16 words.
__device__ __forceinline__ uint2 splitpack2(float f0, float f1) {
    unsigned u0 = __float_as_uint(f0), u1 = __float_as_uint(f1);
    unsigned h0 = u0 & 0xFFFF0000u, h1 = u1 & 0xFFFF0000u;
    float l0 = f0 - __uint_as_float(h0);
    float l1 = f1 - __uint_as_float(h1);
    uint2 r;
    r.x = (h0 >> 16) | h1;
    r.y = (__float_as_uint(l0) >> 16) | (__float_as_uint(l1) & 0xFFFF0000u);
    return r;
}

__device__ __forceinline__ bf16x8 as_bf16x8(int a, int b, int c, int d) {
    union { int4v i; bf16x8 b; } u;
    u.i = (int4v){a, b, c, d};
    return u.b;
}

// ordered-float <-> unsigned monotone encoding (for atomicMax on float)
__device__ __forceinline__ unsigned fenc(float f) {
    unsigned u = __float_as_uint(f);
    return (u & 0x80000000u) ? ~u : (u | 0x80000000u);
}
__device__ __forceinline__ float fdec(unsigned e) {
    return (e & 0x80000000u) ? __uint_as_float(e & 0x7FFFFFFFu) : __uint_as_float(~e);
}

// ---------- dtype sniffer: flag=1 if float inputs are bf16, 0 if fp32 ----------
__global__ void k_sniff(const unsigned short* __restrict__ feat_u16, int* __restrict__ flag) {
    int lane = threadIdx.x;  // 64 threads, 1 wave
    float v = u2f(feat_u16[2 * lane]);
    float av = fabsf(v);
    int ok = (v == 0.f) || (av > 1e-8f && av < 1e8f);
    unsigned long long m = __ballot(ok);
    if (lane == 0) *flag = (__popcll(m) >= 48) ? 1 : 0;
}

// ---------- prep: W [512][64] -> WT hi/lo [64][512] bf16; init h2max encoder ----------
__global__ __launch_bounds__(256) void k_prep(const void* __restrict__ Wv,
                                              const int* __restrict__ flag,
                                              unsigned short* __restrict__ WT_hi,
                                              unsigned short* __restrict__ WT_lo,
                                              unsigned* __restrict__ h2enc) {
    if (blockIdx.x == 0 && threadIdx.x == 0) *h2enc = fenc(-3e38f);
    int idx = blockIdx.x * 256 + threadIdx.x;     // 0..32767
    int k = idx >> 6, c = idx & 63;
    float w = (*flag) ? u2f(((const unsigned short*)Wv)[idx]) : ((const float*)Wv)[idx];
    unsigned u = __float_as_uint(w);
    unsigned hi = u & 0xFFFF0000u;
    float lo = w - __uint_as_float(hi);
    WT_hi[c * IN_DIM + k] = (unsigned short)(hi >> 16);
    WT_lo[c * IN_DIM + k] = (unsigned short)(__float_as_uint(lo) >> 16);
}

// ---------- Kernel A (MFMA): h = feat @ W; hT hi/lo; h1,h2 (pre-scaled by log2e) ----------
// Block = 256 thr (4 waves), 16 rows. Waves split K=512 four ways (4 k-steps each),
// merge through padded LDS; epilogue once per block from the merged tile.
__global__ __launch_bounds__(256) void k_h(const void* __restrict__ featv,
                                           const unsigned short* __restrict__ WT_hi,
                                           const unsigned short* __restrict__ WT_lo,
                                           const void* __restrict__ av,
                                           const int* __restrict__ flag,
                                           float* __restrict__ h1,
                                           float* __restrict__ h2,
                                           unsigned short* __restrict__ hT_hi,
                                           unsigned short* __restrict__ hT_lo,
                                           unsigned* __restrict__ h2enc) {
    __shared__ float C[16][66];        // merged h tile, +2 pad
    const int tid = threadIdx.x;
    const int wave = tid >> 6;
    const int lane = tid & 63;
    const int rsub = lane & 15;
    const int g = lane >> 4;
    const int wrow0 = blockIdx.x * 16;
    const int isbf = *flag;

    f32x4 acc0 = {0.f,0.f,0.f,0.f}, acc1 = {0.f,0.f,0.f,0.f};
    f32x4 acc2 = {0.f,0.f,0.f,0.f}, acc3 = {0.f,0.f,0.f,0.f};

    const int kbeg = wave * (IN_DIM / 4);
    for (int k0 = kbeg; k0 < kbeg + IN_DIM / 4; k0 += 32) {
        const int ka = k0 + g * 8;
        bf16x8 Ah, Al;
        if (isbf) {
            Ah = *(const bf16x8*)((const unsigned short*)featv + (size_t)(wrow0 + rsub) * IN_DIM + ka);
            Al = as_bf16x8(0, 0, 0, 0);
        } else {
            const float* fp = (const float*)featv + (size_t)(wrow0 + rsub) * IN_DIM + ka;
            float4v f0 = *(const float4v*)fp;
            float4v f1 = *(const float4v*)(fp + 4);
            uint2 q0 = splitpack2(f0[0], f0[1]);
            uint2 q1 = splitpack2(f0[2], f0[3]);
            uint2 q2 = splitpack2(f1[0], f1[1]);
            uint2 q3 = splitpack2(f1[2], f1[3]);
            Ah = as_bf16x8((int)q0.x, (int)q1.x, (int)q2.x, (int)q3.x);
            Al = as_bf16x8((int)q0.y, (int)q1.y, (int)q2.y, (int)q3.y);
        }
        const unsigned short* wh = WT_hi + (size_t)rsub * IN_DIM + ka;
        const unsigned short* wl = WT_lo + (size_t)rsub * IN_DIM + ka;
        bf16x8 B0h = *(const bf16x8*)(wh);
        bf16x8 B1h = *(const bf16x8*)(wh + 16 * IN_DIM);
        bf16x8 B2h = *(const bf16x8*)(wh + 32 * IN_DIM);
        bf16x8 B3h = *(const bf16x8*)(wh + 48 * IN_DIM);
        bf16x8 B0l = *(const bf16x8*)(wl);
        bf16x8 B1l = *(const bf16x8*)(wl + 16 * IN_DIM);
        bf16x8 B2l = *(const bf16x8*)(wl + 32 * IN_DIM);
        bf16x8 B3l = *(const bf16x8*)(wl + 48 * IN_DIM);

        acc0 = __builtin_amdgcn_mfma_f32_16x16x32_bf16(Ah, B0h, acc0, 0, 0, 0);
        acc1 = __builtin_amdgcn_mfma_f32_16x16x32_bf16(Ah, B1h, acc1, 0, 0, 0);
        acc2 = __builtin_amdgcn_mfma_f32_16x16x32_bf16(Ah, B2h, acc2, 0, 0, 0);
        acc3 = __builtin_amdgcn_mfma_f32_16x16x32_bf16(Ah, B3h, acc3, 0, 0, 0);
        acc0 = __builtin_amdgcn_mfma_f32_16x16x32_bf16(Ah, B0l, acc0, 0, 0, 0);
        acc1 = __builtin_amdgcn_mfma_f32_16x16x32_bf16(Ah, B1l, acc1, 0, 0, 0);
        acc2 = __builtin_amdgcn_mfma_f32_16x16x32_bf16(Ah, B2l, acc2, 0, 0, 0);
        acc3 = __builtin_amdgcn_mfma_f32_16x16x32_bf16(Ah, B3l, acc3, 0, 0, 0);
        acc0 = __builtin_amdgcn_mfma_f32_16x16x32_bf16(Al, B0h, acc0, 0, 0, 0);
        acc1 = __builtin_amdgcn_mfma_f32_16x16x32_bf16(Al, B1h, acc1, 0, 0, 0);
        acc2 = __builtin_amdgcn_mfma_f32_16x16x32_bf16(Al, B2h, acc2, 0, 0, 0);
        acc3 = __builtin_amdgcn_mfma_f32_16x16x32_bf16(Al, B3h, acc3, 0, 0, 0);
    }

    // merge the 4 K-partials through LDS (C/D layout: col=lane&15, row=4*g+reg)
    if (wave == 0) {
#pragma unroll
        for (int r = 0; r < 4; ++r) {
            C[g * 4 + r][rsub]      = acc0[r];
            C[g * 4 + r][16 + rsub] = acc1[r];
            C[g * 4 + r][32 + rsub] = acc2[r];
            C[g * 4 + r][48 + rsub] = acc3[r];
        }
    }
    __syncthreads();
#pragma unroll
    for (int w2 = 1; w2 < 4; ++w2) {
        if (wave == w2) {
#pragma unroll
            for (int r = 0; r < 4; ++r) {
                C[g * 4 + r][rsub]      += acc0[r];
                C[g * 4 + r][16 + rsub] += acc1[r];
                C[g * 4 + r][32 + rsub] += acc2[r];
                C[g * 4 + r][48 + rsub] += acc3[r];
            }
        }
        __syncthreads();
    }

    // ---- epilogue 1: hT hi/lo split-stores, all 256 threads (4 rows x 1 col each) ----
    {
        int c = tid >> 2;
        int r0 = (tid & 3) * 4;
        float v0 = C[r0 + 0][c], v1 = C[r0 + 1][c], v2 = C[r0 + 2][c], v3 = C[r0 + 3][c];
        uint2 s01 = splitpack2(v0, v1);
        uint2 s23 = splitpack2(v2, v3);
        size_t off = (size_t)c * N + wrow0 + r0;
        { uint2 ph; ph.x = s01.x; ph.y = s23.x; *(uint2*)(hT_hi + off) = ph; }
        { uint2 pl; pl.x = s01.y; pl.y = s23.y; *(uint2*)(hT_lo + off) = pl; }
    }

    // ---- epilogue 2: h1/h2 (scaled by LOG2E) + h2 global max, wave 0 lanes 0-15 ----
    if (wave == 0 && lane < 16) {
        const float* af = (const float*)av;
        const unsigned short* au = (const unsigned short*)av;
        float s1 = 0.f, s2 = 0.f;
#pragma unroll 8
        for (int c = 0; c < 64; ++c) {
            float a1 = isbf ? u2f(au[c])      : af[c];
            float a2 = isbf ? u2f(au[64 + c]) : af[64 + c];
            float hv = C[lane][c];
            s1 += hv * a1;
            s2 += hv * a2;
        }
        s1 *= LOG2E; s2 *= LOG2E;
        h1[wrow0 + lane] = s1;
        h2[wrow0 + lane] = s2;
        float wm = s2;
#pragma unroll
        for (int off = 8; off; off >>= 1) wm = fmaxf(wm, __shfl_xor(wm, off));
        if (lane == 0) atomicMax(h2enc, fenc(wm));
    }
}

// ---------- Kernel B: masked-exp GEMM via MFMA, M_rep=4 ----------
// Block = 64 rows; 4 waves split the k-range 4 ways; each wave computes 4 row-tiles
// (B-frags reused in REGISTERS across the 4 A-tiles -> 4x less hT traffic).
// All values pre-scaled by log2e: e = exp2(leaky(h1'+h2') - M'), exact softmax shift.
__global__ __launch_bounds__(256, 2) void k_attn(const int* __restrict__ adj,
                                                 const float* __restrict__ h1,
                                                 const float* __restrict__ h2,
                                                 const unsigned short* __restrict__ hT_hi,
                                                 const unsigned short* __restrict__ hT_lo,
                                                 const unsigned* __restrict__ h2enc,
                                                 float* __restrict__ pacc,
                                                 float* __restrict__ plner,
                                                 int klen) {
    __shared__ float accs[64][66];     // +2 pad: break g*4-row stride-64 bank aliasing
    __shared__ float lredL[4][64];

    const int wave = threadIdx.x >> 6;
    const int lane = threadIdx.x & 63;
    const int rsub = lane & 15;
    const int g = lane >> 4;
    const int row0 = blockIdx.x * 64;
    const int kbid = blockIdx.y;

    const float h2m = fdec(*h2enc);
    float h1r[4], c0[4];
#pragma unroll
    for (int mt = 0; mt < 4; ++mt) {
        h1r[mt] = h1[row0 + mt * 16 + rsub];
        float u = h1r[mt] + h2m;
        c0[mt] = -fmaxf(u, ALPHA * u);     // -M' (scaled leaky row-max bound)
    }

    f32x4 acc[4][4];
#pragma unroll
    for (int mt = 0; mt < 4; ++mt)
#pragma unroll
        for (int ct = 0; ct < 4; ++ct) acc[mt][ct] = (f32x4){0.f, 0.f, 0.f, 0.f};
    float lacc[4] = {0.f, 0.f, 0.f, 0.f};

    const unsigned short* bph = hT_hi + (size_t)rsub * N;
    const unsigned short* bpl = hT_lo + (size_t)rsub * N;

    const int kbeg = kbid * klen + wave * (klen >> 2);
    const int kend = kbeg + (klen >> 2);
    for (int k0 = kbeg; k0 < kend; k0 += 32) {
        const int kb = k0 + g * 8;

        // B-fragments: loaded once, reused by all 4 M-tiles
        const unsigned short* bh = bph + kb;
        const unsigned short* bl = bpl + kb;
        bf16x8 B0h = *(const bf16x8*)(bh);
        bf16x8 B1h = *(const bf16x8*)(bh + 16 * (size_t)N);
        bf16x8 B2h = *(const bf16x8*)(bh + 32 * (size_t)N);
        bf16x8 B3h = *(const bf16x8*)(bh + 48 * (size_t)N);
        bf16x8 B0l = *(const bf16x8*)(bl);
        bf16x8 B1l = *(const bf16x8*)(bl + 16 * (size_t)N);
        bf16x8 B2l = *(const bf16x8*)(bl + 32 * (size_t)N);
        bf16x8 B3l = *(const bf16x8*)(bl + 48 * (size_t)N);

        float4v hA = *(const float4v*)(h2 + kb);
        float4v hB = *(const float4v*)(h2 + kb + 4);

#pragma unroll
        for (int mt = 0; mt < 4; ++mt) {
            const size_t arow = (size_t)(row0 + mt * 16 + rsub) * N + kb;
            int4v aj0 = *(const int4v*)(adj + arow);
            int4v aj1 = *(const int4v*)(adj + arow + 4);

            float w[8];
#pragma unroll
            for (int j = 0; j < 4; ++j) {
                float u = h1r[mt] + hA[j];
                float s = fmaxf(u, ALPHA * u);
                float e = exp2f(s + c0[mt]);
                w[j] = aj0[j] > 0 ? e : 0.f;
            }
#pragma unroll
            for (int j = 0; j < 4; ++j) {
                float u = h1r[mt] + hB[j];
                float s = fmaxf(u, ALPHA * u);
                float e = exp2f(s + c0[mt]);
                w[4 + j] = aj1[j] > 0 ? e : 0.f;
            }
#pragma unroll
            for (int j = 0; j < 8; ++j) lacc[mt] += w[j];

            uint2 p0 = splitpack2(w[0], w[1]);
            uint2 p1 = splitpack2(w[2], w[3]);
            uint2 p2 = splitpack2(w[4], w[5]);
            uint2 p3 = splitpack2(w[6], w[7]);
            bf16x8 Ahi = as_bf16x8((int)p0.x, (int)p1.x, (int)p2.x, (int)p3.x);
            bf16x8 Alo = as_bf16x8((int)p0.y, (int)p1.y, (int)p2.y, (int)p3.y);

            acc[mt][0] = __builtin_amdgcn_mfma_f32_16x16x32_bf16(Ahi, B0h, acc[mt][0], 0, 0, 0);
            acc[mt][1] = __builtin_amdgcn_mfma_f32_16x16x32_bf16(Ahi, B1h, acc[mt][1], 0, 0, 0);
            acc[mt][2] = __builtin_amdgcn_mfma_f32_16x16x32_bf16(Ahi, B2h, acc[mt][2], 0, 0, 0);
            acc[mt][3] = __builtin_amdgcn_mfma_f32_16x16x32_bf16(Ahi, B3h, acc[mt][3], 0, 0, 0);
            acc[mt][0] = __builtin_amdgcn_mfma_f32_16x16x32_bf16(Ahi, B0l, acc[mt][0], 0, 0, 0);
            acc[mt][1] = __builtin_amdgcn_mfma_f32_16x16x32_bf16(Ahi, B1l, acc[mt][1], 0, 0, 0);
            acc[mt][2] = __builtin_amdgcn_mfma_f32_16x16x32_bf16(Ahi, B2l, acc[mt][2], 0, 0, 0);
            acc[mt][3] = __builtin_amdgcn_mfma_f32_16x16x32_bf16(Ahi, B3l, acc[mt][3], 0, 0, 0);
            acc[mt][0] = __builtin_amdgcn_mfma_f32_16x16x32_bf16(Alo, B0h, acc[mt][0], 0, 0, 0);
            acc[mt][1] = __builtin_amdgcn_mfma_f32_16x16x32_bf16(Alo, B1h, acc[mt][1], 0, 0, 0);
            acc[mt][2] = __builtin_amdgcn_mfma_f32_16x16x32_bf16(Alo, B2h, acc[mt][2], 0, 0, 0);
            acc[mt][3] = __builtin_amdgcn_mfma_f32_16x16x32_bf16(Alo, B3h, acc[mt][3], 0, 0, 0);
        }
    }

    // denominator partials: reduce over the 4 k-groups, one row per (mt, rsub)
#pragma unroll
    for (int mt = 0; mt < 4; ++mt) {
        float l = lacc[mt];
        l += __shfl_xor(l, 16);
        l += __shfl_xor(l, 32);
        if (g == 0) lredL[wave][mt * 16 + rsub] = l;
    }

    // sequential LDS merge of the 4 K-partials (rows shared across waves)
    if (wave == 0) {
#pragma unroll
        for (int mt = 0; mt < 4; ++mt)
#pragma unroll
            for (int ct = 0; ct < 4; ++ct)
#pragma unroll
                for (int r = 0; r < 4; ++r)
                    accs[mt * 16 + g * 4 + r][ct * 16 + rsub] = acc[mt][ct][r];
    }
    __syncthreads();
#pragma unroll
    for (int w2 = 1; w2 < 4; ++w2) {
        if (wave == w2) {
#pragma unroll
            for (int mt = 0; mt < 4; ++mt)
#pragma unroll
                for (int ct = 0; ct < 4; ++ct)
#pragma unroll
                    for (int r = 0; r < 4; ++r)
                        accs[mt * 16 + g * 4 + r][ct * 16 + rsub] += acc[mt][ct][r];
        }
        __syncthreads();
    }

    // coalesced writeout of the block's 64x64 tile + row denominators
    float* pa = pacc + (size_t)kbid * (N * OUT_DIM);
#pragma unroll
    for (int p = 0; p < 16; ++p) {
        int idx = p * 256 + threadIdx.x;
        int rl = idx >> 6, col = idx & 63;
        pa[(size_t)(row0 + rl) * OUT_DIM + col] = accs[rl][col];
    }
    if (threadIdx.x < 64)
        plner[(size_t)kbid * N + row0 + threadIdx.x] =
            lredL[0][threadIdx.x] + lredL[1][threadIdx.x] + lredL[2][threadIdx.x] + lredL[3][threadIdx.x];
}

// ---------- Kernel C: merge K-partials, normalize, ELU, store ----------
__global__ __launch_bounds__(256) void k_out(const float* __restrict__ pacc,
                                             const float* __restrict__ plner,
                                             const int* __restrict__ flag,
                                             void* __restrict__ outv,
                                             int nkb) {
    int idx = blockIdx.x * 256 + threadIdx.x;
    int row = idx >> 6;
    float v = 0.f, l = 0.f;
    for (int kb = 0; kb < nkb; ++kb) {
        v += pacc[(size_t)kb * (N * OUT_DIM) + idx];
        l += plner[(size_t)kb * N + row];
    }
    float o = l > 0.f ? v / l : 0.f;
    o = o > 0.f ? o : exp2f(o * LOG2E) - 1.f;               // ELU
    if (*flag) ((bf16*)outv)[idx] = __float2bfloat16(o);
    else       ((float*)outv)[idx] = o;
}

extern "C" void kernel_launch(void* const* d_in, const int* in_sizes, int n_in,
                              void* d_out, int out_size, void* d_ws, size_t ws_size,
                              hipStream_t stream) {
    const void* feat = d_in[0];
    const int* adj = (const int*)d_in[1];
    const void* W = d_in[2];
    const void* a = d_in[3];

    char* ws = (char*)d_ws;
    int*      flag  = (int*)(ws);
    unsigned* h2enc = (unsigned*)(ws + 256);
    float* h1       = (float*)(ws + 4096);                              // 32 KB
    float* h2       = (float*)(ws + 36864);                             // 32 KB
    unsigned short* hT_hi = (unsigned short*)(ws + 69632);              // 1 MB
    unsigned short* hT_lo = (unsigned short*)(ws + 69632 + 1048576);    // 1 MB
    unsigned short* WT_hi = (unsigned short*)(ws + 2166784);            // 64 KB
    unsigned short* WT_lo = (unsigned short*)(ws + 2166784 + 65536);    // 64 KB
    char* dynbase = ws + 2297856;

    size_t cap = ws_size ? ws_size : ((size_t)1 << 30);
    int nkb = 8;
    while (nkb > 1) {
        size_t need = 2297856 + (size_t)nkb * ((size_t)N * OUT_DIM * 4 + (size_t)N * 4);
        if (need <= cap) break;
        nkb >>= 1;
    }
    float* pacc  = (float*)dynbase;
    float* plner = (float*)(dynbase + (size_t)nkb * N * OUT_DIM * 4);

    hipLaunchKernelGGL(k_sniff, dim3(1), dim3(64), 0, stream,
                       (const unsigned short*)feat, flag);
    hipLaunchKernelGGL(k_prep, dim3((IN_DIM * OUT_DIM) / 256), dim3(256), 0, stream,
                       W, flag, WT_hi, WT_lo, h2enc);
    hipLaunchKernelGGL(k_h, dim3(N / 16), dim3(256), 0, stream,
                       feat, WT_hi, WT_lo, a, flag, h1, h2, hT_hi, hT_lo, h2enc);
    hipLaunchKernelGGL(k_attn, dim3(N / 64, nkb), dim3(256), 0, stream,
                       adj, h1, h2, hT_hi, hT_lo, h2enc, pacc, plner, N / nkb);
    hipLaunchKernelGGL(k_out, dim3((N * OUT_DIM) / 256), dim3(256), 0, stream,
                       pacc, plner, flag, d_out, nkb);
}